// Round 9
// baseline (109.628 us; speedup 1.0000x reference)
//
#include <hip/hip_runtime.h>
#include <hip/hip_fp16.h>
#include <math.h>

#define BATCH 8
#define H 480
#define W 640
#define HW (H * W)

// ---- single-launch geometry: all 16 steps fused ----
#define PS 16                 // fused steps (= total)
#define PTX 96                // output tile width
#define PTY 32                // output tile height
#define PRX 128               // region cols = PTX + 2*PS (= 64 lanes x 2)
#define PRY 64                // region rows = PTY + 2*PS
#define NT 1024               // 16 waves; wave = strip of 4 rows, lane = col-pair
#define RPT 4                 // rows per thread

// DPP wave-wide shifts (GFX9/CDNA): lane i <- lane i-1 (0x138), lane i+1 (0x130).
// Shifted-in lanes take `old` (=0): region col -1 / col 128 read as 0, which
// only feeds rim pixels (trapezoid-stale-safe) or out-of-image pixels (w=0).
__device__ __forceinline__ float dppL(float v) {   // value from lane-1
    return __int_as_float(__builtin_amdgcn_update_dpp(
        0, __float_as_int(v), 0x138, 0xF, 0xF, false));
}
__device__ __forceinline__ float dppR(float v) {   // value from lane+1
    return __int_as_float(__builtin_amdgcn_update_dpp(
        0, __float_as_int(v), 0x130, 0xF, 0xF, false));
}
__device__ __forceinline__ unsigned pk2(float a, float b) {
    unsigned lo = __half_as_ushort(__float2half_rn(a));
    unsigned hi = __half_as_ushort(__float2half_rn(b));
    return lo | (hi << 16);
}

// Mixed-precision FMA: acc += f16(lo/hi half of q) * xv, single VOP3P instr,
// no separate cvt. op_sel_hi[0]=1 marks src0 as fp16; op_sel[0] picks the half.
__device__ __forceinline__ void fmix_lo(float& acc, unsigned q, float xv) {
    asm("v_fma_mix_f32 %0, %1, %2, %0 op_sel:[0,0,0] op_sel_hi:[1,0,0]"
        : "+v"(acc) : "v"(q), "v"(xv));
}
__device__ __forceinline__ void fmix_hi(float& acc, unsigned q, float xv) {
    asm("v_fma_mix_f32 %0, %1, %2, %0 op_sel:[1,0,0] op_sel_hi:[1,0,0]"
        : "+v"(acc) : "v"(q), "v"(xv));
}
// acc = f16(hi half of q) * 1.0 + 0  (bias extract, one instruction)
__device__ __forceinline__ float bias_hi(unsigned q, float one) {
    float r;
    asm("v_fma_mix_f32 %0, %1, %2, 0 op_sel:[1,0,0] op_sel_hi:[1,0,0]"
        : "=v"(r) : "v"(q), "v"(one));
    return r;
}

// window of one LDS row for this lane's 2 px: {c-1, c, c+1, c+2}
__device__ __forceinline__ float4 ldrow(const float* rowp, int lane) {
    const float2 v = *(const float2*)(rowp + 2 * lane);
    float4 w;
    w.x = dppL(v.y);      // col c-1 = left pair's .y
    w.y = v.x;
    w.z = v.y;
    w.w = dppR(v.x);      // col c+2 = right pair's .x
    return w;
}

__global__ __launch_bounds__(NT) void prop16_kernel(
    const float* __restrict__ guided,   // (B,9,H,W)
    const float* __restrict__ x,        // (B,1,H,W)
    const float* __restrict__ sparse,   // (B,1,H,W)
    float* __restrict__ xout)           // (B,1,H,W)
{
    __shared__ float xs[2][PRY][PRX];   // 65,536 B, no pads (DPP handles +-1 col)

    const int tid  = threadIdx.x;
    const int lane = tid & 63;          // col pair (0..63)
    const int strip = tid >> 6;         // wave id = strip (0..15)
    const int r0 = strip * RPT;
    const int b = blockIdx.z;
    const int bx0 = blockIdx.x * PTX, by0 = blockIdx.y * PTY;
    const int gx0 = bx0 - PS, gy0 = by0 - PS;
    const size_t ob = (size_t)b * HW;

    // ---- fill buf0 with x region (float2 pairs; all-or-nothing since gx even) ----
    {
        const int gx = gx0 + 2 * lane;
        const bool cok = (gx >= 0) && (gx < W);
#pragma unroll
        for (int j = 0; j < 4; ++j) {
            const int r = strip + 16 * j;
            const int gy = gy0 + r;
            float2 v = make_float2(0.f, 0.f);
            if (cok && gy >= 0 && gy < H)
                v = *(const float2*)(x + ob + (size_t)gy * W + gx);
            *(float2*)&xs[0][r][2 * lane] = v;
        }
    }
    __syncthreads();

    // ---- inline softmax + mask fold for own 2x4 px -> 40 weight u32 ----
    unsigned qe0[RPT], qe1[RPT], qe2[RPT], qe3[RPT], qe4[RPT];
    unsigned qo0[RPT], qo1[RPT], qo2[RPT], qo3[RPT], qo4[RPT];
    {
        const int gx = gx0 + 2 * lane;
        const bool cok = (gx >= 0) && (gx < W);
#pragma unroll
        for (int i = 0; i < RPT; ++i) {
            const int r = r0 + i;
            const int gy = gy0 + r;
            if (cok && gy >= 0 && gy < H) {
                const size_t p = (size_t)gy * W + gx;
                float2 g[9];
                float mex = -INFINITY, mey = -INFINITY;
#pragma unroll
                for (int k = 0; k < 9; ++k) {
                    g[k] = *(const float2*)(guided + ((size_t)(b * 9 + k)) * HW + p);
                    mex = fmaxf(mex, g[k].x);
                    mey = fmaxf(mey, g[k].y);
                }
                float se = 0.f, so = 0.f;
#pragma unroll
                for (int k = 0; k < 9; ++k) {
                    g[k].x = __expf(g[k].x - mex); se += g[k].x;
                    g[k].y = __expf(g[k].y - mey); so += g[k].y;
                }
                const float2 sv = *(const float2*)(sparse + ob + p);
                const float maske = (sv.x > 0.f) ? 1.f : 0.f;
                const float masko = (sv.y > 0.f) ? 1.f : 0.f;
                const float sce = (1.f - maske) / se;
                const float sco = (1.f - masko) / so;
                qe0[i] = pk2(g[0].x * sce, g[1].x * sce);
                qe1[i] = pk2(g[2].x * sce, g[3].x * sce);
                qe2[i] = pk2(g[4].x * sce, g[5].x * sce);
                qe3[i] = pk2(g[6].x * sce, g[7].x * sce);
                qe4[i] = pk2(g[8].x * sce, maske * xs[0][r][2 * lane]);
                qo0[i] = pk2(g[0].y * sco, g[1].y * sco);
                qo1[i] = pk2(g[2].y * sco, g[3].y * sco);
                qo2[i] = pk2(g[4].y * sco, g[5].y * sco);
                qo3[i] = pk2(g[6].y * sco, g[7].y * sco);
                qo4[i] = pk2(g[8].y * sco, masko * xs[0][r][2 * lane + 1]);
            } else {
                qe0[i] = qe1[i] = qe2[i] = qe3[i] = qe4[i] = 0u;
                qo0[i] = qo1[i] = qo2[i] = qo3[i] = qo4[i] = 0u;
            }
        }
    }

    const int rm1 = (strip == 0) ? 0 : (r0 - 1);          // clamped rim rows
    const int rb3 = (strip == 15) ? (PRY - 1) : (r0 + RPT);
    const float fone = 1.0f;

    // ---- 16 Jacobi steps, double-buffered, 1 barrier/step ----
    for (int t = 0; t < PS; ++t) {
        const float (*rd)[PRX] = xs[t & 1];
        float (*wr)[PRX] = xs[(t + 1) & 1];

        float4 T = ldrow(&rd[rm1][0], lane);
        float4 M = ldrow(&rd[r0][0], lane);
#pragma unroll
        for (int i = 0; i < RPT; ++i) {
            const int rb = (i == RPT - 1) ? rb3 : (r0 + i + 1);
            const float4 Bw = ldrow(&rd[rb][0], lane);
            // even px (col 2*lane): window cols {x,y,z} of each row
            float ae = bias_hi(qe4[i], fone);
            fmix_lo(ae, qe0[i], T.x);
            fmix_hi(ae, qe0[i], T.y);
            fmix_lo(ae, qe1[i], T.z);
            fmix_hi(ae, qe1[i], M.x);
            fmix_lo(ae, qe2[i], M.y);
            fmix_hi(ae, qe2[i], M.z);
            fmix_lo(ae, qe3[i], Bw.x);
            fmix_hi(ae, qe3[i], Bw.y);
            fmix_lo(ae, qe4[i], Bw.z);
            // odd px (col 2*lane+1): window cols {y,z,w}
            float ao = bias_hi(qo4[i], fone);
            fmix_lo(ao, qo0[i], T.y);
            fmix_hi(ao, qo0[i], T.z);
            fmix_lo(ao, qo1[i], T.w);
            fmix_hi(ao, qo1[i], M.y);
            fmix_lo(ao, qo2[i], M.z);
            fmix_hi(ao, qo2[i], M.w);
            fmix_lo(ao, qo3[i], Bw.y);
            fmix_hi(ao, qo3[i], Bw.z);
            fmix_lo(ao, qo4[i], Bw.w);
            *(float2*)&wr[r0 + i][2 * lane] = make_float2(ae, ao);
            T = M; M = Bw;
        }
        __syncthreads();      // wr complete before it becomes rd
    }

    // ---- after 16 steps final values in buf0; write tile (coalesced) ----
    for (int i = tid; i < PTX * PTY; i += NT) {
        const int r = i / PTX, cc = i - r * PTX;
        const int gx = bx0 + cc;
        if (gx < W)
            xout[ob + (size_t)(by0 + r) * W + gx] = xs[0][PS + r][PS + cc];
    }
}

extern "C" void kernel_launch(void* const* d_in, const int* in_sizes, int n_in,
                              void* d_out, int out_size, void* d_ws, size_t ws_size,
                              hipStream_t stream) {
    const float* guided = (const float*)d_in[0];
    const float* x      = (const float*)d_in[1];
    const float* sparse = (const float*)d_in[2];
    float* out = (float*)d_out;

    dim3 blk(NT, 1, 1);
    dim3 grd((W + PTX - 1) / PTX, H / PTY, BATCH);   // 7 x 15 x 8 = 840 blocks
    prop16_kernel<<<grd, blk, 0, stream>>>(guided, x, sparse, out);
}